// Round 5
// baseline (1504.579 us; speedup 1.0000x reference)
//
#include <hip/hip_runtime.h>
#include <hip/hip_bf16.h>

typedef __bf16 bf16_t;
typedef __bf16 bf16x8 __attribute__((ext_vector_type(8)));
typedef __bf16 bf16x4 __attribute__((ext_vector_type(4)));
typedef float  f32x4  __attribute__((ext_vector_type(4)));

// ---------------- workspace layout (bytes) ----------------
// WBF: bf16 [72 ntile][12 kk][64 lane][8]  qkv weights in MFMA B-frag order
//      (ntile = h*6 + tct; tct: 0,1=q 2,3=k 4,5=v halves; col=ntile*16+lo, k=kk*32+hi*8+j)
#define WBT_OFF   0                                  // 442368 bf16 = 884736 B
// PWF: bf16 [24 ntile][12 kk][64 lane][8]  proj weights in B-frag order (col=ntile*16+lo)
#define PWB_OFF   (72*12*512*2)                      // 884736
#define BIASL_OFF (PWB_OFF + 24*12*512*2)            // 1179648: f32 [12][4][4][64][4] attn bias C-frag (-1e30 for j>=49)
#define QKVB_OFF  (BIASL_OFF + 12*4*4*64*4*4)        // 1376256: f32 [1152] qkv bias remapped
#define QKV_OFF   1380864                            // bf16 [4096][12][3][64*32] padded Q(scaled)/K/V^T tiles
#define QKV_BYTES (4096ULL*12*3*2048*2)              // 603,979,776
#define O_OFF     (QKV_OFF + QKV_BYTES)              // 605,360,640
#define O_BYTES   (200704ULL*384*2)                  // bf16 [200704][384] attn output
#define WS_NEED   (O_OFF + O_BYTES)                  // 759,501,312

__global__ void prep_kernel(const float* __restrict__ qkv_w,
                            const float* __restrict__ qkv_b,
                            const float* __restrict__ proj_w,
                            const float* __restrict__ rpb,
                            const int*   __restrict__ rel_idx,
                            char* __restrict__ ws)
{
    const int n_wbf  = 72*12*512;    // 442368
    const int n_pwf  = 24*12*512;    // 147456
    const int n_bias = 12*4*4*64*4;  // 49152
    const int n_qb   = 1152;
    int idx = blockIdx.x * blockDim.x + threadIdx.x;
    if (idx < n_wbf) {
        int j = idx & 7, lane = (idx >> 3) & 63;
        int t = idx >> 9;
        int kk = t % 12, ntile = t / 12;
        int lo = lane & 15, hi = lane >> 4;
        int h = ntile / 6, tct = ntile % 6, s = tct >> 1, db = (tct & 1) << 4;
        ((bf16_t*)(ws + WBT_OFF))[idx] =
            (bf16_t)qkv_w[(s*384 + h*32 + db + lo)*384 + kk*32 + hi*8 + j];
    } else if (idx < n_wbf + n_pwf) {
        int li = idx - n_wbf;
        int j = li & 7, lane = (li >> 3) & 63;
        int t = li >> 9;
        int kk = t % 12, ntile = t / 12;
        int lo = lane & 15, hi = lane >> 4;
        ((bf16_t*)(ws + PWB_OFF))[li] =
            (bf16_t)proj_w[(ntile*16 + lo)*384 + kk*32 + hi*8 + j];
    } else if (idx < n_wbf + n_pwf + n_bias) {
        int li = idx - n_wbf - n_pwf;          // [h][m][ct][l][r]
        int r  = li & 3;
        int l  = (li >> 2) & 63;
        int ct = (li >> 8) & 3;
        int m  = (li >> 10) & 3;
        int h  = li >> 12;
        int i  = m*16 + ((l >> 4) << 2) + r;   // token row
        int jj = ct*16 + (l & 15);             // token col
        float v;
        if (jj >= 49)     v = -1e30f;          // mask padded key columns
        else if (i < 49)  v = rpb[rel_idx[i*49 + jj]*12 + h];
        else              v = 0.f;
        ((float*)(ws + BIASL_OFF))[li] = v;
    } else if (idx < n_wbf + n_pwf + n_bias + n_qb) {
        int i = idx - n_wbf - n_pwf - n_bias;  // ntile*16 + lo
        int h = i / 96, c = i % 96;
        int s = c >> 5, cc = c & 31;
        ((float*)(ws + QKVB_OFF))[i] = qkv_b[s*384 + h*32 + cc];
    }
}

// K1: qkv projection GEMM. 1 block = 1 window, all 1152 cols in 3 passes.
// wave: 64 rows x 48 cols per pass; B-frags contiguous 1KB loads from WBF.
__launch_bounds__(512, 4)
__global__ void qkv_gemm_kernel(const float* __restrict__ x,
                                char* __restrict__ ws)
{
    __shared__ __attribute__((aligned(16))) char smem[49152]; // bf16 [64][384] swizzled

    const int tid = threadIdx.x;
    const int lane = tid & 63, lo = lane & 15, hi = lane >> 4;
    const int w = tid >> 6;
    const int wi = blockIdx.x;

    auto xs_addr = [&](int row, int kb) { return row*768 + (kb ^ ((row & 7) << 4)); };

    uint4 z4 = make_uint4(0u,0u,0u,0u);
    for (int c = tid; c < 15*48; c += 512) {            // zero pad rows 49..63
        int row = 49 + c/48, kc = c%48;
        *(uint4*)(smem + xs_addr(row, kc*16)) = z4;
    }
    const float* xw = x + (size_t)wi * (49*384);
    for (int c = tid; c < 49*48; c += 512) {            // stage x fp32->bf16
        int row = c/48, kc = c%48;
        float4 f0 = *(const float4*)(xw + row*384 + kc*8);
        float4 f1 = *(const float4*)(xw + row*384 + kc*8 + 4);
        bf16x8 t;
        t[0]=(bf16_t)f0.x; t[1]=(bf16_t)f0.y; t[2]=(bf16_t)f0.z; t[3]=(bf16_t)f0.w;
        t[4]=(bf16_t)f1.x; t[5]=(bf16_t)f1.y; t[6]=(bf16_t)f1.z; t[7]=(bf16_t)f1.w;
        *(bf16x8*)(smem + xs_addr(row, kc*16)) = t;
    }
    __syncthreads();

    const bf16_t* WBF   = (const bf16_t*)(ws + WBT_OFF);
    const float*  biasQ = (const float*)(ws + QKVB_OFF);
    const float scale = 0.17677669529663687f; // 1/sqrt(32)
    bf16_t* qkv = (bf16_t*)(ws + QKV_OFF) + (size_t)wi*12*3*2048;

#pragma unroll 1
    for (int pass = 0; pass < 3; ++pass) {
        const int cg = pass*8 + w;                       // col-group 0..23 (48 cols each)
        const bf16_t* bb = WBF + (size_t)cg*(3*12*512) + (lane << 3);

        f32x4 acc[4][3];
#pragma unroll
        for (int m = 0; m < 4; ++m)
#pragma unroll
            for (int nt = 0; nt < 3; ++nt) acc[m][nt] = f32x4{0.f,0.f,0.f,0.f};

#pragma unroll
        for (int kk = 0; kk < 12; ++kk) {
            bf16x8 a[4];
#pragma unroll
            for (int m = 0; m < 4; ++m)
                a[m] = *(const bf16x8*)(smem + xs_addr(m*16 + lo, kk*64 + hi*16));
#pragma unroll
            for (int nt = 0; nt < 3; ++nt) {
                bf16x8 b = *(const bf16x8*)(bb + ((nt*12 + kk) << 9));
#pragma unroll
                for (int m = 0; m < 4; ++m)
                    acc[m][nt] = __builtin_amdgcn_mfma_f32_16x16x32_bf16(a[m], b, acc[m][nt], 0,0,0);
            }
        }

        // epilogue: bias add + scatter to Q(scaled)/K row-major [64][32], V^T [32][64]
#pragma unroll
        for (int nt = 0; nt < 3; ++nt) {
            const int ntile = cg*3 + nt;
            const int h = ntile / 6, tct = ntile % 6;
            const int s = tct >> 1, db = (tct & 1) << 4;
            float bq = biasQ[ntile*16 + lo];
            bf16_t* base = qkv + (h*3 + s)*2048;
            if (s < 2) {
                const float sc = (s == 0) ? scale : 1.0f;
#pragma unroll
                for (int m = 0; m < 4; ++m)
#pragma unroll
                    for (int r = 0; r < 4; ++r)
                        base[(m*16 + hi*4 + r)*32 + db + lo] = (bf16_t)((acc[m][nt][r] + bq) * sc);
            } else {
#pragma unroll
                for (int m = 0; m < 4; ++m) {
                    bf16x4 p;
#pragma unroll
                    for (int r = 0; r < 4; ++r) p[r] = (bf16_t)(acc[m][nt][r] + bq);
                    *(bf16x4*)(base + (db + lo)*64 + m*16 + hi*4) = p;
                }
            }
        }
    }
}

// K2: attention. 1 wave = 1 (window, head); no barriers.
__launch_bounds__(256)
__global__ void attn_kernel(char* __restrict__ ws)
{
    __shared__ __attribute__((aligned(16))) char smem[4*9216]; // P bf16 [64][72] per wave

    const int tid = threadIdx.x, lane = tid & 63, lo = lane & 15, hi = lane >> 4;
    const int wv = tid >> 6;
    const int w  = blockIdx.x;
    const int h  = blockIdx.y*4 + wv;
    char* P = smem + wv*9216;
    const char*   base = ws + QKV_OFF + (size_t)(w*12 + h)*12288;
    const float4* bL   = (const float4*)(ws + BIASL_OFF) + (size_t)h*16*64;

    bf16x8 aq[4], bk[4];
#pragma unroll
    for (int m = 0; m < 4; ++m)  aq[m]  = *(const bf16x8*)(base + (m*16+lo)*64 + hi*16);
#pragma unroll
    for (int ct = 0; ct < 4; ++ct) bk[ct] = *(const bf16x8*)(base + 4096 + (ct*16+lo)*64 + hi*16);

    const f32x4 zz = {0.f,0.f,0.f,0.f};
#pragma unroll
    for (int m = 0; m < 4; ++m) {
        f32x4 s[4];
#pragma unroll
        for (int ct = 0; ct < 4; ++ct) {
            s[ct] = __builtin_amdgcn_mfma_f32_16x16x32_bf16(aq[m], bk[ct], zz, 0,0,0);
            float4 bv = bL[(m*4 + ct)*64 + lane];
            s[ct][0]+=bv.x; s[ct][1]+=bv.y; s[ct][2]+=bv.z; s[ct][3]+=bv.w;
        }
#pragma unroll
        for (int r = 0; r < 4; ++r) {
            float mx = fmaxf(fmaxf(s[0][r],s[1][r]), fmaxf(s[2][r],s[3][r]));
#pragma unroll
            for (int off = 1; off < 16; off <<= 1) mx = fmaxf(mx, __shfl_xor(mx, off));
            float e0 = __expf(s[0][r]-mx), e1 = __expf(s[1][r]-mx);
            float e2 = __expf(s[2][r]-mx), e3 = __expf(s[3][r]-mx);
            float sum = e0+e1+e2+e3;
#pragma unroll
            for (int off = 1; off < 16; off <<= 1) sum += __shfl_xor(sum, off);
            float rinv = 1.0f / sum;
            int row = m*16 + hi*4 + r;
            *(bf16_t*)(P + row*144 + (0*16+lo)*2) = (bf16_t)(e0*rinv);
            *(bf16_t*)(P + row*144 + (1*16+lo)*2) = (bf16_t)(e1*rinv);
            *(bf16_t*)(P + row*144 + (2*16+lo)*2) = (bf16_t)(e2*rinv);
            *(bf16_t*)(P + row*144 + (3*16+lo)*2) = (bf16_t)(e3*rinv);
        }
    }
    asm volatile("s_waitcnt lgkmcnt(0)" ::: "memory");

    bf16_t* O = (bf16_t*)(ws + O_OFF);
#pragma unroll
    for (int m = 0; m < 4; ++m) {
#pragma unroll
        for (int dt = 0; dt < 2; ++dt) {
            f32x4 o = zz;
#pragma unroll
            for (int ks = 0; ks < 2; ++ks) {
                bf16x8 ap = *(const bf16x8*)(P + (m*16+lo)*144 + ks*64 + hi*16);
                bf16x8 bv = *(const bf16x8*)(base + 8192 + (dt*16+lo)*128 + ks*64 + hi*16);
                o = __builtin_amdgcn_mfma_f32_16x16x32_bf16(ap, bv, o, 0,0,0);
            }
#pragma unroll
            for (int r = 0; r < 4; ++r) {
                int row = m*16 + hi*4 + r;
                if (row < 49)
                    O[((size_t)w*49 + row)*384 + h*32 + dt*16 + lo] = (bf16_t)o[r];
            }
        }
    }
}

// K3: output projection GEMM. 1 block = 64 tokens; wave = 64 rows x 48 cols.
__launch_bounds__(512, 4)
__global__ void proj_gemm_kernel(const float* __restrict__ proj_b,
                                 const char* __restrict__ ws,
                                 float* __restrict__ out)
{
    __shared__ __attribute__((aligned(16))) char smem[49152];

    const int tid = threadIdx.x;
    const int lane = tid & 63, lo = lane & 15, hi = lane >> 4;
    const int w = tid >> 6;
    const int mb = blockIdx.x;

    auto xs_addr = [&](int row, int kb) { return row*768 + (kb ^ ((row & 7) << 4)); };

    const bf16_t* O = (const bf16_t*)(ws + O_OFF) + (size_t)mb*64*384;
    for (int c = tid; c < 64*48; c += 512) {
        int row = c/48, kc = c%48;
        uint4 d = *(const uint4*)(O + row*384 + kc*8);
        *(uint4*)(smem + xs_addr(row, kc*16)) = d;
    }
    __syncthreads();

    const bf16_t* PWF = (const bf16_t*)(ws + PWB_OFF);
    const bf16_t* bb  = PWF + (size_t)w*(3*12*512) + (lane << 3);

    f32x4 acc[4][3];
#pragma unroll
    for (int m = 0; m < 4; ++m)
#pragma unroll
        for (int nt = 0; nt < 3; ++nt) acc[m][nt] = f32x4{0.f,0.f,0.f,0.f};

#pragma unroll
    for (int kk = 0; kk < 12; ++kk) {
        bf16x8 a[4];
#pragma unroll
        for (int m = 0; m < 4; ++m)
            a[m] = *(const bf16x8*)(smem + xs_addr(m*16 + lo, kk*64 + hi*16));
#pragma unroll
        for (int nt = 0; nt < 3; ++nt) {
            bf16x8 b = *(const bf16x8*)(bb + ((nt*12 + kk) << 9));
#pragma unroll
            for (int m = 0; m < 4; ++m)
                acc[m][nt] = __builtin_amdgcn_mfma_f32_16x16x32_bf16(a[m], b, acc[m][nt], 0,0,0);
        }
    }

    float* ow = out + (size_t)mb*64*384;
#pragma unroll
    for (int nt = 0; nt < 3; ++nt) {
        int cc = (w*3 + nt)*16 + lo;
        float pb = proj_b[cc];
#pragma unroll
        for (int m = 0; m < 4; ++m)
#pragma unroll
            for (int r = 0; r < 4; ++r)
                ow[(m*16 + hi*4 + r)*384 + cc] = acc[m][nt][r] + pb;
    }
}

extern "C" void kernel_launch(void* const* d_in, const int* in_sizes, int n_in,
                              void* d_out, int out_size, void* d_ws, size_t ws_size,
                              hipStream_t stream)
{
    const float* x      = (const float*)d_in[0];
    const float* qkv_w  = (const float*)d_in[1];
    const float* qkv_b  = (const float*)d_in[2];
    const float* proj_w = (const float*)d_in[3];
    const float* proj_b = (const float*)d_in[4];
    const float* rpb    = (const float*)d_in[5];
    const int*   rel_idx= (const int*)d_in[6];
    char* ws = (char*)d_ws;

    const int total = 72*12*512 + 24*12*512 + 12*4*4*64*4 + 1152;
    prep_kernel<<<(total + 255)/256, 256, 0, stream>>>(qkv_w, qkv_b, proj_w, rpb, rel_idx, ws);

    qkv_gemm_kernel<<<4096, 512, 0, stream>>>(x, ws);
    attn_kernel<<<dim3(4096, 3), 256, 0, stream>>>(ws);
    proj_gemm_kernel<<<3136, 512, 0, stream>>>(proj_b, ws, (float*)d_out);
}

// Round 6
// 702.426 us; speedup vs baseline: 2.1420x; 2.1420x over previous
//
#include <hip/hip_runtime.h>
#include <hip/hip_bf16.h>

typedef __bf16 bf16_t;
typedef __bf16 bf16x8 __attribute__((ext_vector_type(8)));
typedef __bf16 bf16x4 __attribute__((ext_vector_type(4)));
typedef float  f32x4  __attribute__((ext_vector_type(4)));

// ---------------- workspace layout (bytes) ----------------
// WBF: bf16 [72 ntile][12 kk][64 lane][8]  qkv weights in MFMA B-frag order
//      (ntile = h*6 + tct; tct: 0,1=q 2,3=k 4,5=v halves; col=ntile*16+lo, k=kk*32+hi*8+j)
#define WBT_OFF   0                                  // 884736 B
// PWF: bf16 [24 ntile][12 kk][64 lane][8]  proj weights in B-frag order (col=ntile*16+lo)
#define PWB_OFF   (72*12*512*2)                      // 884736
#define BIASL_OFF (PWB_OFF + 24*12*512*2)            // f32 [12][4][4][64][4] attn bias C-frag (-1e30 for j>=49)
#define QKVB_OFF  (BIASL_OFF + 12*4*4*64*4*4)        // f32 [1152] qkv bias remapped
// total ws needed = QKVB_OFF + 1152*4 = 1,380,864 B

// ---------------- LDS layout (bytes) ----------------
// XS: bf16 [64][384] row stride 768, XOR-swizzled                      @ 0      (49152)
// per head-local hl (stride 23040) @ 49152:
//   QS  bf16 [64] rows, stride 72   (+0,    4608)
//   KS  bf16 [64] rows, stride 72   (+4608, 4608)
//   VT  bf16 [32] rows, stride 144  (+9216, 4608)
//   P   bf16 [64] rows, stride 144  (+13824,9216)
// O: bf16 [64] rows, stride 272 @ 141312 (17408)
#define L_HEAD   49152
#define L_HSTR   23040
#define L_O      141312
#define L_TOT    158720

__global__ void prep_kernel(const float* __restrict__ qkv_w,
                            const float* __restrict__ qkv_b,
                            const float* __restrict__ proj_w,
                            const float* __restrict__ rpb,
                            const int*   __restrict__ rel_idx,
                            char* __restrict__ ws)
{
    const int n_wbf  = 72*12*512;    // 442368
    const int n_pwf  = 24*12*512;    // 147456
    const int n_bias = 12*4*4*64*4;  // 49152
    const int n_qb   = 1152;
    int idx = blockIdx.x * blockDim.x + threadIdx.x;
    if (idx < n_wbf) {
        int j = idx & 7, lane = (idx >> 3) & 63;
        int t = idx >> 9;
        int kk = t % 12, ntile = t / 12;
        int lo = lane & 15, hi = lane >> 4;
        int h = ntile / 6, tct = ntile % 6, s = tct >> 1, db = (tct & 1) << 4;
        ((bf16_t*)(ws + WBT_OFF))[idx] =
            (bf16_t)qkv_w[(s*384 + h*32 + db + lo)*384 + kk*32 + hi*8 + j];
    } else if (idx < n_wbf + n_pwf) {
        int li = idx - n_wbf;
        int j = li & 7, lane = (li >> 3) & 63;
        int t = li >> 9;
        int kk = t % 12, ntile = t / 12;
        int lo = lane & 15, hi = lane >> 4;
        ((bf16_t*)(ws + PWB_OFF))[li] =
            (bf16_t)proj_w[(ntile*16 + lo)*384 + kk*32 + hi*8 + j];
    } else if (idx < n_wbf + n_pwf + n_bias) {
        int li = idx - n_wbf - n_pwf;          // [h][m][ct][l][r]
        int r  = li & 3;
        int l  = (li >> 2) & 63;
        int ct = (li >> 8) & 3;
        int m  = (li >> 10) & 3;
        int h  = li >> 12;
        int i  = m*16 + ((l >> 4) << 2) + r;   // token row
        int jj = ct*16 + (l & 15);             // token col
        float v;
        if (jj >= 49)     v = -1e30f;          // mask padded key columns
        else if (i < 49)  v = rpb[rel_idx[i*49 + jj]*12 + h];
        else              v = 0.f;
        ((float*)(ws + BIASL_OFF))[li] = v;
    } else if (idx < n_wbf + n_pwf + n_bias + n_qb) {
        int i = idx - n_wbf - n_pwf - n_bias;  // ntile*16 + lo
        int h = i / 96, c = i % 96;
        int s = c >> 5, cc = c & 31;
        ((float*)(ws + QKVB_OFF))[i] = qkv_b[s*384 + h*32 + cc];
    }
}

// Fully fused: qkv GEMM -> attention -> proj GEMM, one block per window.
__launch_bounds__(512, 2)
__global__ void fused_attn_kernel(const float* __restrict__ x,
                                  const float* __restrict__ proj_b,
                                  const char*  __restrict__ ws,
                                  float* __restrict__ out)
{
    __shared__ __attribute__((aligned(16))) char smem[L_TOT];

    const int tid = threadIdx.x;
    const int lane = tid & 63, lo = lane & 15, hi = lane >> 4;
    const int w = tid >> 6;
    const int wi = blockIdx.x;

    auto xs_addr = [&](int row, int kb) { return row*768 + (kb ^ ((row & 7) << 4)); };

    // ---- stage x (fp32 -> bf16, swizzled), zero pad rows ----
    uint4 z4 = make_uint4(0u,0u,0u,0u);
    for (int c = tid; c < 15*48; c += 512) {
        int row = 49 + c/48, kc = c%48;
        *(uint4*)(smem + xs_addr(row, kc*16)) = z4;
    }
    const float* xw = x + (size_t)wi * (49*384);
    for (int c = tid; c < 49*48; c += 512) {
        int row = c/48, kc = c%48;
        float4 f0 = *(const float4*)(xw + row*384 + kc*8);
        float4 f1 = *(const float4*)(xw + row*384 + kc*8 + 4);
        bf16x8 t;
        t[0]=(bf16_t)f0.x; t[1]=(bf16_t)f0.y; t[2]=(bf16_t)f0.z; t[3]=(bf16_t)f0.w;
        t[4]=(bf16_t)f1.x; t[5]=(bf16_t)f1.y; t[6]=(bf16_t)f1.z; t[7]=(bf16_t)f1.w;
        *(bf16x8*)(smem + xs_addr(row, kc*16)) = t;
    }
    __syncthreads();

    const bf16_t* WBF   = (const bf16_t*)(ws + WBT_OFF);
    const bf16_t* PWF   = (const bf16_t*)(ws + PWB_OFF);
    const float*  biasQ = (const float*)(ws + QKVB_OFF);
    const float scale = 0.17677669529663687f; // 1/sqrt(32)
    const f32x4 zz = {0.f,0.f,0.f,0.f};

    f32x4 accP[4][3];
#pragma unroll
    for (int m = 0; m < 4; ++m)
#pragma unroll
        for (int nt = 0; nt < 3; ++nt) accP[m][nt] = zz;

    const int hl_a = w >> 1;          // attention: head-local handled by this wave
    const int mh   = w & 1;           // attention: m-half (m-tiles 2mh, 2mh+1)
    char* HA = smem + L_HEAD + hl_a*L_HSTR;

#pragma unroll 1
    for (int pass = 0; pass < 3; ++pass) {
        // ======== phase 1: QKV GEMM for heads 4*pass .. 4*pass+3 ========
        {
            const bf16_t* bb = WBF + (size_t)(pass*8 + w)*(3*12*512) + (lane << 3);
            f32x4 acc[4][3];
#pragma unroll
            for (int m = 0; m < 4; ++m)
#pragma unroll
                for (int nt = 0; nt < 3; ++nt) acc[m][nt] = zz;

            bf16x8 br[3][3];
#pragma unroll
            for (int k = 0; k < 2; ++k)
#pragma unroll
                for (int nt = 0; nt < 3; ++nt)
                    br[k][nt] = *(const bf16x8*)(bb + ((nt*12 + k) << 9));

#pragma unroll
            for (int kk = 0; kk < 12; ++kk) {
                if (kk < 10) {
#pragma unroll
                    for (int nt = 0; nt < 3; ++nt)
                        br[(kk+2)%3][nt] = *(const bf16x8*)(bb + ((nt*12 + kk+2) << 9));
                }
                bf16x8 a[4];
#pragma unroll
                for (int m = 0; m < 4; ++m)
                    a[m] = *(const bf16x8*)(smem + xs_addr(m*16 + lo, kk*64 + hi*16));
#pragma unroll
                for (int nt = 0; nt < 3; ++nt)
#pragma unroll
                    for (int m = 0; m < 4; ++m)
                        acc[m][nt] = __builtin_amdgcn_mfma_f32_16x16x32_bf16(a[m], br[kk%3][nt], acc[m][nt], 0,0,0);
            }

            // epilogue -> LDS Q(scaled)/K rows stride 72, V^T rows stride 144
#pragma unroll
            for (int nt = 0; nt < 3; ++nt) {
                const int ntl = w*3 + nt;             // 0..23 within pass
                const int hl = ntl / 6, tct = ntl % 6;
                const int s = tct >> 1, db = (tct & 1) << 4;
                float bq = biasQ[(pass*24 + ntl)*16 + lo];
                char* hb = smem + L_HEAD + hl*L_HSTR;
                if (s == 0) {
#pragma unroll
                    for (int m = 0; m < 4; ++m)
#pragma unroll
                        for (int r = 0; r < 4; ++r)
                            *(bf16_t*)(hb + (m*16 + hi*4 + r)*72 + (db + lo)*2) =
                                (bf16_t)((acc[m][nt][r] + bq) * scale);
                } else if (s == 1) {
#pragma unroll
                    for (int m = 0; m < 4; ++m)
#pragma unroll
                        for (int r = 0; r < 4; ++r)
                            *(bf16_t*)(hb + 4608 + (m*16 + hi*4 + r)*72 + (db + lo)*2) =
                                (bf16_t)(acc[m][nt][r] + bq);
                } else {
#pragma unroll
                    for (int m = 0; m < 4; ++m) {
                        bf16x4 p;
#pragma unroll
                        for (int r = 0; r < 4; ++r) p[r] = (bf16_t)(acc[m][nt][r] + bq);
                        *(bf16x4*)(hb + 9216 + (db + lo)*144 + (m*16 + hi*4)*2) = p;
                    }
                }
            }
        }
        __syncthreads();

        // ======== phase 2: attention for head 4*pass + hl_a (2 waves/head) ========
        {
            const char* QS = HA;
            const char* KS = HA + 4608;
            const char* VT = HA + 9216;
            char*       P  = HA + 13824;
            const float4* bL = (const float4*)(ws + BIASL_OFF) + (size_t)(pass*4 + hl_a)*1024;

            bf16x8 aq[2], bk[4];
#pragma unroll
            for (int mi = 0; mi < 2; ++mi)
                aq[mi] = *(const bf16x8*)(QS + ((mh*2 + mi)*16 + lo)*72 + hi*16);
#pragma unroll
            for (int ct = 0; ct < 4; ++ct)
                bk[ct] = *(const bf16x8*)(KS + (ct*16 + lo)*72 + hi*16);

#pragma unroll
            for (int mi = 0; mi < 2; ++mi) {
                const int m = mh*2 + mi;
                f32x4 s[4];
#pragma unroll
                for (int ct = 0; ct < 4; ++ct) {
                    s[ct] = __builtin_amdgcn_mfma_f32_16x16x32_bf16(aq[mi], bk[ct], zz, 0,0,0);
                    float4 bv = bL[(m*4 + ct)*64 + lane];
                    s[ct][0]+=bv.x; s[ct][1]+=bv.y; s[ct][2]+=bv.z; s[ct][3]+=bv.w;
                }
#pragma unroll
                for (int r = 0; r < 4; ++r) {
                    float mx = fmaxf(fmaxf(s[0][r],s[1][r]), fmaxf(s[2][r],s[3][r]));
#pragma unroll
                    for (int off = 1; off < 16; off <<= 1) mx = fmaxf(mx, __shfl_xor(mx, off));
                    float e0 = __expf(s[0][r]-mx), e1 = __expf(s[1][r]-mx);
                    float e2 = __expf(s[2][r]-mx), e3 = __expf(s[3][r]-mx);
                    float sum = e0+e1+e2+e3;
#pragma unroll
                    for (int off = 1; off < 16; off <<= 1) sum += __shfl_xor(sum, off);
                    float rinv = 1.0f / sum;
                    int row = m*16 + hi*4 + r;
                    *(bf16_t*)(P + row*144 + (0*16+lo)*2) = (bf16_t)(e0*rinv);
                    *(bf16_t*)(P + row*144 + (1*16+lo)*2) = (bf16_t)(e1*rinv);
                    *(bf16_t*)(P + row*144 + (2*16+lo)*2) = (bf16_t)(e2*rinv);
                    *(bf16_t*)(P + row*144 + (3*16+lo)*2) = (bf16_t)(e3*rinv);
                }
            }
            asm volatile("s_waitcnt lgkmcnt(0)" ::: "memory");

            // PV -> O LDS tile (cols hl_a*32 + dt*16 + lo, stride 272)
#pragma unroll
            for (int mi = 0; mi < 2; ++mi) {
                const int m = mh*2 + mi;
#pragma unroll
                for (int dt = 0; dt < 2; ++dt) {
                    f32x4 o = zz;
#pragma unroll
                    for (int ks = 0; ks < 2; ++ks) {
                        bf16x8 ap = *(const bf16x8*)(P  + (m*16+lo)*144 + ks*64 + hi*16);
                        bf16x8 bv = *(const bf16x8*)(VT + (dt*16+lo)*144 + ks*64 + hi*16);
                        o = __builtin_amdgcn_mfma_f32_16x16x32_bf16(ap, bv, o, 0,0,0);
                    }
                    const int c2 = (hl_a*32 + dt*16 + lo)*2;
#pragma unroll
                    for (int r = 0; r < 4; ++r)
                        *(bf16_t*)(smem + L_O + (m*16 + hi*4 + r)*272 + c2) = (bf16_t)o[r];
                }
            }
        }
        __syncthreads();

        // ======== phase 3: proj partial accumulation (k-cols 128*pass..+127) ========
        {
            bf16x8 bp[2][3];
#pragma unroll
            for (int nt = 0; nt < 3; ++nt)
                bp[0][nt] = *(const bf16x8*)(PWF + (size_t)(((w*3 + nt)*12 + pass*4) << 9) + (lane << 3));
#pragma unroll
            for (int kk2 = 0; kk2 < 4; ++kk2) {
                if (kk2 < 3) {
#pragma unroll
                    for (int nt = 0; nt < 3; ++nt)
                        bp[(kk2+1)&1][nt] = *(const bf16x8*)(PWF + (size_t)(((w*3 + nt)*12 + pass*4 + kk2+1) << 9) + (lane << 3));
                }
                bf16x8 ao[4];
#pragma unroll
                for (int m = 0; m < 4; ++m)
                    ao[m] = *(const bf16x8*)(smem + L_O + (m*16 + lo)*272 + kk2*64 + hi*16);
#pragma unroll
                for (int nt = 0; nt < 3; ++nt)
#pragma unroll
                    for (int m = 0; m < 4; ++m)
                        accP[m][nt] = __builtin_amdgcn_mfma_f32_16x16x32_bf16(ao[m], bp[kk2&1][nt], accP[m][nt], 0,0,0);
            }
        }
        __syncthreads();   // protect O tile (and QS/KS/VT/P) for next pass
    }

    // ---- epilogue: add proj bias, store fp32 ----
    float* ow = out + (size_t)wi * (49*384);
#pragma unroll
    for (int nt = 0; nt < 3; ++nt) {
        int cc = (w*3 + nt)*16 + lo;
        float pb = proj_b[cc];
#pragma unroll
        for (int m = 0; m < 4; ++m)
#pragma unroll
            for (int r = 0; r < 4; ++r) {
                int row = m*16 + hi*4 + r;
                if (row < 49) ow[row*384 + cc] = accP[m][nt][r] + pb;
            }
    }
}

extern "C" void kernel_launch(void* const* d_in, const int* in_sizes, int n_in,
                              void* d_out, int out_size, void* d_ws, size_t ws_size,
                              hipStream_t stream)
{
    const float* x      = (const float*)d_in[0];
    const float* qkv_w  = (const float*)d_in[1];
    const float* qkv_b  = (const float*)d_in[2];
    const float* proj_w = (const float*)d_in[3];
    const float* proj_b = (const float*)d_in[4];
    const float* rpb    = (const float*)d_in[5];
    const int*   rel_idx= (const int*)d_in[6];
    char* ws = (char*)d_ws;

    const int total = 72*12*512 + 24*12*512 + 12*4*4*64*4 + 1152;
    prep_kernel<<<(total + 255)/256, 256, 0, stream>>>(qkv_w, qkv_b, proj_w, rpb, rel_idx, ws);
    fused_attn_kernel<<<4096, 512, 0, stream>>>(x, proj_b, ws, (float*)d_out);
}